// Round 1
// baseline (284.368 us; speedup 1.0000x reference)
//
#include <hip/hip_runtime.h>
#include <hip/hip_bf16.h>

#define T_TOK 2048
#define DDIM  1024
#define HDIM  2048
#define NEXP  8
#define NSEG  9   // 8 routed + 1 shared

typedef unsigned short u16;
typedef __attribute__((ext_vector_type(4))) float f32x4;
typedef __attribute__((ext_vector_type(8))) short bf16x8;
typedef __attribute__((ext_vector_type(4))) unsigned short u16x4;

__device__ __forceinline__ u16 f2bf(float x) {
  union { float f; unsigned int u; } v; v.f = x;
  unsigned int r = v.u + 0x7fffu + ((v.u >> 16) & 1u);
  return (u16)(r >> 16);
}
__device__ __forceinline__ float gelu_exact(float x) {
  return 0.5f * x * (1.0f + erff(x * 0.70710678118654752f));
}

__device__ __forceinline__ void gload16(const void* g, void* l) {
  __builtin_amdgcn_global_load_lds(
      (const __attribute__((address_space(1))) unsigned int*)g,
      (__attribute__((address_space(3))) unsigned int*)l, 16, 0, 0);
}

// ---------------- router: logits, softmax, top-2, lists, bf16 X ----------------
__global__ __launch_bounds__(256) void router_kernel(
    const float* __restrict__ x, const float* __restrict__ rw,
    const float* __restrict__ rb, u16* __restrict__ xb,
    float* __restrict__ weights, int* __restrict__ counts,
    int* __restrict__ lists)
{
  int wv = threadIdx.x >> 6, lane = threadIdx.x & 63;
  int t = blockIdx.x * 4 + wv;            // one wave per token
  const float* xrow = x + (size_t)t * DDIM;
  float acc[NEXP];
#pragma unroll
  for (int e = 0; e < NEXP; e++) acc[e] = 0.f;
#pragma unroll
  for (int i = 0; i < 4; i++) {
    int d0 = i * 256 + lane * 4;
    f32x4 xv = *(const f32x4*)(xrow + d0);
    u16x4 pk;
#pragma unroll
    for (int j = 0; j < 4; j++) {
      float xs = xv[j];
      pk[j] = f2bf(xs);
      const float* wr = rw + (size_t)(d0 + j) * NEXP;
#pragma unroll
      for (int e = 0; e < NEXP; e++) acc[e] = fmaf(xs, wr[e], acc[e]);
    }
    *(u16x4*)(xb + (size_t)t * DDIM + d0) = pk;
  }
#pragma unroll
  for (int off = 32; off >= 1; off >>= 1)
#pragma unroll
    for (int e = 0; e < NEXP; e++) acc[e] += __shfl_xor(acc[e], off);

  if (lane == 0) {
    float lg[NEXP], mx = -1e30f;
#pragma unroll
    for (int e = 0; e < NEXP; e++) { lg[e] = acc[e] + rb[e]; mx = fmaxf(mx, lg[e]); }
    float p[NEXP], s = 0.f;
#pragma unroll
    for (int e = 0; e < NEXP; e++) { p[e] = expf(lg[e] - mx); s += p[e]; }
    float inv = 1.0f / s;
#pragma unroll
    for (int e = 0; e < NEXP; e++) p[e] *= inv;
    int i1 = 0;
#pragma unroll
    for (int e = 1; e < NEXP; e++) if (p[e] > p[i1]) i1 = e;
    int i2 = (i1 == 0) ? 1 : 0;
#pragma unroll
    for (int e = 0; e < NEXP; e++) if (e != i1 && p[e] > p[i2]) i2 = e;
#pragma unroll
    for (int e = 0; e < NEXP; e++)
      weights[(size_t)t * NEXP + e] = (e == i1) ? p[i1] : (e == i2) ? p[i2] : 0.f;
    int p1 = atomicAdd(counts + i1, 1); lists[i1 * T_TOK + p1] = t;
    int p2 = atomicAdd(counts + i2, 1); lists[i2 * T_TOK + p2] = t;
    lists[NEXP * T_TOK + t] = t;        // shared segment: identity
  }
}

__global__ void seg_kernel(int* counts, int* segoff) {
  counts[NEXP] = T_TOK;
  int off = 0;
  for (int e = 0; e < NSEG; e++) { segoff[e] = off; off += counts[e]; }
}

// ------------- transpose + fp32->bf16 cast: in [B][R][C] -> out [B][C][R] -------------
__global__ __launch_bounds__(256) void transpose_bf16_kernel(
    const float* __restrict__ in, u16* __restrict__ out, int R, int C)
{
  __shared__ float tile[32][33];
  int b = blockIdx.z;
  int r0 = blockIdx.y * 32, c0 = blockIdx.x * 32;
  const float* inb = in + (size_t)b * R * C;
  u16* outb = out + (size_t)b * R * C;
  int tx = threadIdx.x & 31, ty = threadIdx.x >> 5;
#pragma unroll
  for (int j = 0; j < 4; j++) {
    int r = ty + j * 8;
    tile[r][tx] = inb[(size_t)(r0 + r) * C + c0 + tx];
  }
  __syncthreads();
#pragma unroll
  for (int j = 0; j < 4; j++) {
    int rr = ty + j * 8;
    outb[(size_t)(c0 + rr) * R + r0 + tx] = f2bf(tile[tx][rr]);
  }
}

// ---------------- GEMM1: H1 = gelu(gather(X) @ W1 + b1), bf16 out ----------------
__global__ __launch_bounds__(256) void gemm1_kernel(
    const u16* __restrict__ Xb, const u16* __restrict__ rw1t,
    const u16* __restrict__ sw1t, const float* __restrict__ rb1,
    const float* __restrict__ sb1, const int* __restrict__ counts,
    const int* __restrict__ segoff, const int* __restrict__ lists,
    u16* __restrict__ H1)
{
  int e = blockIdx.z;
  int cnt = counts[e];
  int m0 = blockIdx.y * 128;
  if (m0 >= cnt) return;
  int n0 = blockIdx.x * 128;
  const u16* Bt = (e < NEXP) ? (rw1t + (size_t)e * HDIM * DDIM) : sw1t;
  const float* bias = (e < NEXP) ? (rb1 + (size_t)e * HDIM) : sb1;
  const int* list = lists + e * T_TOK;
  int seg = segoff[e];

  __shared__ u16 Alds[128 * 64];
  __shared__ u16 Blds[128 * 64];

  int tid = threadIdx.x, wv = tid >> 6, lane = tid & 63;
  int wm = wv >> 1, wn = wv & 1;
  int col8 = (lane & 7) * 8;

  size_t asrc[4], bsrc[4];
#pragma unroll
  for (int r = 0; r < 4; r++) {
    int srow = r * 32 + wv * 8 + (lane >> 3);
    int tok = list[min(m0 + srow, cnt - 1)];
    asrc[r] = (size_t)tok * DDIM + col8;
    bsrc[r] = (size_t)(n0 + srow) * DDIM + col8;
  }

  f32x4 acc[4][4];
#pragma unroll
  for (int i = 0; i < 4; i++)
#pragma unroll
    for (int j = 0; j < 4; j++) acc[i][j] = (f32x4){0.f, 0.f, 0.f, 0.f};

  for (int kk = 0; kk < DDIM; kk += 64) {
#pragma unroll
    for (int r = 0; r < 4; r++) {
      gload16(Xb + asrc[r] + kk, Alds + (size_t)(r * 256 + wv * 64 + lane) * 8);
      gload16(Bt + bsrc[r] + kk, Blds + (size_t)(r * 256 + wv * 64 + lane) * 8);
    }
    __syncthreads();
#pragma unroll
    for (int ks = 0; ks < 2; ks++) {
      int kb = ks * 32 + (lane >> 4) * 8;
      bf16x8 af[4], bfr[4];
#pragma unroll
      for (int f = 0; f < 4; f++) {
        af[f]  = *(const bf16x8*)(Alds + (wm * 64 + f * 16 + (lane & 15)) * 64 + kb);
        bfr[f] = *(const bf16x8*)(Blds + (wn * 64 + f * 16 + (lane & 15)) * 64 + kb);
      }
#pragma unroll
      for (int mf = 0; mf < 4; mf++)
#pragma unroll
        for (int nf = 0; nf < 4; nf++)
          acc[mf][nf] = __builtin_amdgcn_mfma_f32_16x16x32_bf16(af[mf], bfr[nf], acc[mf][nf], 0, 0, 0);
    }
    __syncthreads();
  }

#pragma unroll
  for (int nf = 0; nf < 4; nf++) {
    int col = n0 + wn * 64 + nf * 16 + (lane & 15);
    float b = bias[col];
#pragma unroll
    for (int mf = 0; mf < 4; mf++) {
#pragma unroll
      for (int rg = 0; rg < 4; rg++) {
        int mt = wm * 64 + mf * 16 + (lane >> 4) * 4 + rg;
        if (m0 + mt < cnt) {
          float v = acc[mf][nf][rg] + b;
          H1[(size_t)(seg + m0 + mt) * HDIM + col] = f2bf(gelu_exact(v));
        }
      }
    }
  }
}

// ------------- GEMM2: out[tok] += w * (H1seg @ W2 + b2), fp32 atomics -------------
__global__ __launch_bounds__(256) void gemm2_kernel(
    const u16* __restrict__ H1, const u16* __restrict__ rw2t,
    const u16* __restrict__ sw2t, const float* __restrict__ rb2,
    const float* __restrict__ sb2, const float* __restrict__ weights,
    const int* __restrict__ counts, const int* __restrict__ segoff,
    const int* __restrict__ lists, float* __restrict__ out)
{
  int e = blockIdx.z;
  int cnt = counts[e];
  int m0 = blockIdx.y * 128;
  if (m0 >= cnt) return;
  int n0 = blockIdx.x * 128;
  const u16* Bt = (e < NEXP) ? (rw2t + (size_t)e * DDIM * HDIM) : sw2t;
  const float* bias = (e < NEXP) ? (rb2 + (size_t)e * DDIM) : sb2;
  const int* list = lists + e * T_TOK;
  int seg = segoff[e];

  __shared__ u16 Alds[128 * 64];
  __shared__ u16 Blds[128 * 64];

  int tid = threadIdx.x, wv = tid >> 6, lane = tid & 63;
  int wm = wv >> 1, wn = wv & 1;
  int col8 = (lane & 7) * 8;

  size_t asrc[4], bsrc[4];
#pragma unroll
  for (int r = 0; r < 4; r++) {
    int srow = r * 32 + wv * 8 + (lane >> 3);
    asrc[r] = (size_t)(seg + min(m0 + srow, cnt - 1)) * HDIM + col8;
    bsrc[r] = (size_t)(n0 + srow) * HDIM + col8;
  }

  f32x4 acc[4][4];
#pragma unroll
  for (int i = 0; i < 4; i++)
#pragma unroll
    for (int j = 0; j < 4; j++) acc[i][j] = (f32x4){0.f, 0.f, 0.f, 0.f};

  for (int kk = 0; kk < HDIM; kk += 64) {
#pragma unroll
    for (int r = 0; r < 4; r++) {
      gload16(H1 + asrc[r] + kk, Alds + (size_t)(r * 256 + wv * 64 + lane) * 8);
      gload16(Bt + bsrc[r] + kk, Blds + (size_t)(r * 256 + wv * 64 + lane) * 8);
    }
    __syncthreads();
#pragma unroll
    for (int ks = 0; ks < 2; ks++) {
      int kb = ks * 32 + (lane >> 4) * 8;
      bf16x8 af[4], bfr[4];
#pragma unroll
      for (int f = 0; f < 4; f++) {
        af[f]  = *(const bf16x8*)(Alds + (wm * 64 + f * 16 + (lane & 15)) * 64 + kb);
        bfr[f] = *(const bf16x8*)(Blds + (wn * 64 + f * 16 + (lane & 15)) * 64 + kb);
      }
#pragma unroll
      for (int mf = 0; mf < 4; mf++)
#pragma unroll
        for (int nf = 0; nf < 4; nf++)
          acc[mf][nf] = __builtin_amdgcn_mfma_f32_16x16x32_bf16(af[mf], bfr[nf], acc[mf][nf], 0, 0, 0);
    }
    __syncthreads();
  }

#pragma unroll
  for (int nf = 0; nf < 4; nf++) {
    int col = n0 + wn * 64 + nf * 16 + (lane & 15);
    float b = bias[col];
#pragma unroll
    for (int mf = 0; mf < 4; mf++) {
#pragma unroll
      for (int rg = 0; rg < 4; rg++) {
        int mt = wm * 64 + mf * 16 + (lane >> 4) * 4 + rg;
        int mrow = m0 + mt;
        if (mrow < cnt) {
          int tok = list[mrow];
          float w = (e < NEXP) ? weights[(size_t)tok * NEXP + e] : 1.0f;
          atomicAdd(out + (size_t)tok * DDIM + col, w * (acc[mf][nf][rg] + b));
        }
      }
    }
  }
}

// ---------------- launcher ----------------
extern "C" void kernel_launch(void* const* d_in, const int* in_sizes, int n_in,
                              void* d_out, int out_size, void* d_ws, size_t ws_size,
                              hipStream_t stream) {
  (void)in_sizes; (void)n_in; (void)out_size; (void)ws_size;
  const float* hidden   = (const float*)d_in[0];
  const float* router_w = (const float*)d_in[1];
  const float* router_b = (const float*)d_in[2];
  const float* sw1 = (const float*)d_in[3];
  const float* sb1 = (const float*)d_in[4];
  const float* sw2 = (const float*)d_in[5];
  const float* sb2 = (const float*)d_in[6];
  const float* rw1 = (const float*)d_in[7];
  const float* rb1 = (const float*)d_in[8];
  const float* rw2 = (const float*)d_in[9];
  const float* rb2 = (const float*)d_in[10];
  float* out = (float*)d_out;

  char* ws = (char*)d_ws;
  // ws layout (bytes), all 16B aligned; total ~100.1 MB
  u16* Xb      = (u16*)(ws + 0);            //  4,194,304  [T][D] bf16
  u16* rw1t    = (u16*)(ws + 4194304);      // 33,554,432  [E][H][D] bf16 (B^T)
  u16* rw2t    = (u16*)(ws + 37748736);     // 33,554,432  [E][D][H] bf16 (B^T)
  u16* sw1t    = (u16*)(ws + 71303168);     //  4,194,304  [H][D]
  u16* sw2t    = (u16*)(ws + 75497472);     //  4,194,304  [D][H]
  u16* H1      = (u16*)(ws + 79691776);     // 25,165,824  [6144][H] bf16
  float* weights = (float*)(ws + 104857600);//     65,536  [T][E]
  int* counts  = (int*)(ws + 104923136);    //         64
  int* segoff  = (int*)(ws + 104923200);    //         64
  int* lists   = (int*)(ws + 104923264);    //     73,728  [NSEG][T]

  hipMemsetAsync(counts, 0, 64, stream);
  hipMemsetAsync(out, 0, (size_t)T_TOK * DDIM * sizeof(float), stream);

  router_kernel<<<T_TOK / 4, 256, 0, stream>>>(hidden, router_w, router_b, Xb,
                                               weights, counts, lists);
  seg_kernel<<<1, 1, 0, stream>>>(counts, segoff);

  transpose_bf16_kernel<<<dim3(HDIM / 32, DDIM / 32, NEXP), 256, 0, stream>>>(rw1, rw1t, DDIM, HDIM);
  transpose_bf16_kernel<<<dim3(DDIM / 32, HDIM / 32, NEXP), 256, 0, stream>>>(rw2, rw2t, HDIM, DDIM);
  transpose_bf16_kernel<<<dim3(HDIM / 32, DDIM / 32, 1), 256, 0, stream>>>(sw1, sw1t, DDIM, HDIM);
  transpose_bf16_kernel<<<dim3(DDIM / 32, HDIM / 32, 1), 256, 0, stream>>>(sw2, sw2t, HDIM, DDIM);

  gemm1_kernel<<<dim3(HDIM / 128, T_TOK / 128, NSEG), 256, 0, stream>>>(
      Xb, rw1t, sw1t, rb1, sb1, counts, segoff, lists, H1);
  gemm2_kernel<<<dim3(DDIM / 128, T_TOK / 128, NSEG), 256, 0, stream>>>(
      H1, rw2t, sw2t, rb2, sb2, weights, counts, segoff, lists, out);
}

// Round 2
// 256.077 us; speedup vs baseline: 1.1105x; 1.1105x over previous
//
#include <hip/hip_runtime.h>
#include <hip/hip_bf16.h>

#define T_TOK 2048
#define DDIM  1024
#define HDIM  2048
#define NEXP  8
#define NSEG  9   // 8 routed + 1 shared

typedef unsigned short u16;
typedef __attribute__((ext_vector_type(4))) float f32x4;
typedef __attribute__((ext_vector_type(8))) short bf16x8;
typedef __attribute__((ext_vector_type(4))) unsigned short u16x4;

__device__ __forceinline__ u16 f2bf(float x) {
  union { float f; unsigned int u; } v; v.f = x;
  unsigned int r = v.u + 0x7fffu + ((v.u >> 16) & 1u);
  return (u16)(r >> 16);
}
__device__ __forceinline__ float gelu_exact(float x) {
  return 0.5f * x * (1.0f + erff(x * 0.70710678118654752f));
}

__device__ __forceinline__ void gload16(const void* g, void* l) {
  __builtin_amdgcn_global_load_lds(
      (const __attribute__((address_space(1))) unsigned int*)g,
      (__attribute__((address_space(3))) unsigned int*)l, 16, 0, 0);
}

// ---------------- router: logits, softmax, top-2, lists, bf16 X ----------------
__global__ __launch_bounds__(256) void router_kernel(
    const float* __restrict__ x, const float* __restrict__ rw,
    const float* __restrict__ rb, u16* __restrict__ xb,
    float* __restrict__ weights, int* __restrict__ counts,
    int* __restrict__ lists)
{
  int wv = threadIdx.x >> 6, lane = threadIdx.x & 63;
  int t = blockIdx.x * 4 + wv;            // one wave per token
  const float* xrow = x + (size_t)t * DDIM;
  float acc[NEXP];
#pragma unroll
  for (int e = 0; e < NEXP; e++) acc[e] = 0.f;
#pragma unroll
  for (int i = 0; i < 4; i++) {
    int d0 = i * 256 + lane * 4;
    f32x4 xv = *(const f32x4*)(xrow + d0);
    u16x4 pk;
#pragma unroll
    for (int j = 0; j < 4; j++) {
      float xs = xv[j];
      pk[j] = f2bf(xs);
      const float* wr = rw + (size_t)(d0 + j) * NEXP;
#pragma unroll
      for (int e = 0; e < NEXP; e++) acc[e] = fmaf(xs, wr[e], acc[e]);
    }
    *(u16x4*)(xb + (size_t)t * DDIM + d0) = pk;
  }
#pragma unroll
  for (int off = 32; off >= 1; off >>= 1)
#pragma unroll
    for (int e = 0; e < NEXP; e++) acc[e] += __shfl_xor(acc[e], off);

  if (lane == 0) {
    float lg[NEXP], mx = -1e30f;
#pragma unroll
    for (int e = 0; e < NEXP; e++) { lg[e] = acc[e] + rb[e]; mx = fmaxf(mx, lg[e]); }
    float p[NEXP], s = 0.f;
#pragma unroll
    for (int e = 0; e < NEXP; e++) { p[e] = expf(lg[e] - mx); s += p[e]; }
    float inv = 1.0f / s;
#pragma unroll
    for (int e = 0; e < NEXP; e++) p[e] *= inv;
    int i1 = 0;
#pragma unroll
    for (int e = 1; e < NEXP; e++) if (p[e] > p[i1]) i1 = e;
    int i2 = (i1 == 0) ? 1 : 0;
#pragma unroll
    for (int e = 0; e < NEXP; e++) if (e != i1 && p[e] > p[i2]) i2 = e;
#pragma unroll
    for (int e = 0; e < NEXP; e++)
      weights[(size_t)t * NEXP + e] = (e == i1) ? p[i1] : (e == i2) ? p[i2] : 0.f;
    int p1 = atomicAdd(counts + i1, 1); lists[i1 * T_TOK + p1] = t;
    int p2 = atomicAdd(counts + i2, 1); lists[i2 * T_TOK + p2] = t;
    lists[NEXP * T_TOK + t] = t;        // shared segment: identity
  }
}

// seg offsets + compact y-tile table: ytab[i] = e*256 + my for every
// non-empty 128-row tile. Removes empty-block dispatches entirely.
__global__ void seg_kernel(int* counts, int* segoff, int* ytab, int* nyt) {
  counts[NEXP] = T_TOK;
  int off = 0, n = 0;
  for (int e = 0; e < NSEG; e++) {
    segoff[e] = off;
    int c = counts[e];
    for (int my = 0; my * 128 < c; my++) ytab[n++] = e * 256 + my;
    off += c;
  }
  *nyt = n;
}

// ------------- transpose + fp32->bf16 cast: [z][R][C] -> [z][C][R] -------------
// z<NEXP selects the routed stack, z==NEXP the shared weight.
__global__ __launch_bounds__(256) void transpose_bf16_kernel(
    const float* __restrict__ rin, const float* __restrict__ sin_,
    u16* __restrict__ rout, u16* __restrict__ sout, int R, int C)
{
  __shared__ float tile[32][33];
  int b = blockIdx.z;
  const float* inb = (b < NEXP) ? rin + (size_t)b * R * C : sin_;
  u16* outb = (b < NEXP) ? rout + (size_t)b * R * C : sout;
  int r0 = blockIdx.y * 32, c0 = blockIdx.x * 32;
  int tx = threadIdx.x & 31, ty = threadIdx.x >> 5;
#pragma unroll
  for (int j = 0; j < 4; j++) {
    int r = ty + j * 8;
    tile[r][tx] = inb[(size_t)(r0 + r) * C + c0 + tx];
  }
  __syncthreads();
#pragma unroll
  for (int j = 0; j < 4; j++) {
    int rr = ty + j * 8;
    outb[(size_t)(c0 + rr) * R + r0 + tx] = f2bf(tile[tx][rr]);
  }
}

// ---------------- GEMM1: H1 = gelu(gather(X) @ W1 + b1), bf16 out ----------------
__global__ __launch_bounds__(256) void gemm1_kernel(
    const u16* __restrict__ Xb, const u16* __restrict__ rw1t,
    const u16* __restrict__ sw1t, const float* __restrict__ rb1,
    const float* __restrict__ sb1, const int* __restrict__ counts,
    const int* __restrict__ segoff, const int* __restrict__ lists,
    const int* __restrict__ ytab, const int* __restrict__ nyt,
    u16* __restrict__ H1)
{
  __shared__ u16 Alds[128 * 64];
  __shared__ u16 Blds[128 * 64];

  int tid = threadIdx.x, wv = tid >> 6, lane = tid & 63;
  int wm = wv >> 1, wn = wv & 1;
  int col8 = (lane & 7) * 8;

  int ntile = nyt[0] * (HDIM / 128);
  for (int t = blockIdx.x; t < ntile; t += gridDim.x) {
    int yt = t >> 4, nx = t & 15;
    int em = ytab[yt];
    int e = em >> 8, m0 = (em & 255) * 128, n0 = nx * 128;
    int cnt = counts[e];
    const u16* Bt = (e < NEXP) ? (rw1t + (size_t)e * HDIM * DDIM) : sw1t;
    const float* bias = (e < NEXP) ? (rb1 + (size_t)e * HDIM) : sb1;
    const int* list = lists + e * T_TOK;
    int seg = segoff[e];

    size_t asrc[4], bsrc[4];
#pragma unroll
    for (int r = 0; r < 4; r++) {
      int srow = r * 32 + wv * 8 + (lane >> 3);
      int tok = list[min(m0 + srow, cnt - 1)];
      asrc[r] = (size_t)tok * DDIM + col8;
      bsrc[r] = (size_t)(n0 + srow) * DDIM + col8;
    }

    f32x4 acc[4][4];
#pragma unroll
    for (int i = 0; i < 4; i++)
#pragma unroll
      for (int j = 0; j < 4; j++) acc[i][j] = (f32x4){0.f, 0.f, 0.f, 0.f};

    for (int kk = 0; kk < DDIM; kk += 64) {
#pragma unroll
      for (int r = 0; r < 4; r++) {
        gload16(Xb + asrc[r] + kk, Alds + (size_t)(r * 256 + wv * 64 + lane) * 8);
        gload16(Bt + bsrc[r] + kk, Blds + (size_t)(r * 256 + wv * 64 + lane) * 8);
      }
      __syncthreads();
#pragma unroll
      for (int ks = 0; ks < 2; ks++) {
        int kb = ks * 32 + (lane >> 4) * 8;
        bf16x8 af[4], bfr[4];
#pragma unroll
        for (int f = 0; f < 4; f++) {
          af[f]  = *(const bf16x8*)(Alds + (wm * 64 + f * 16 + (lane & 15)) * 64 + kb);
          bfr[f] = *(const bf16x8*)(Blds + (wn * 64 + f * 16 + (lane & 15)) * 64 + kb);
        }
#pragma unroll
        for (int mf = 0; mf < 4; mf++)
#pragma unroll
          for (int nf = 0; nf < 4; nf++)
            acc[mf][nf] = __builtin_amdgcn_mfma_f32_16x16x32_bf16(af[mf], bfr[nf], acc[mf][nf], 0, 0, 0);
      }
      __syncthreads();
    }

#pragma unroll
    for (int nf = 0; nf < 4; nf++) {
      int col = n0 + wn * 64 + nf * 16 + (lane & 15);
      float b = bias[col];
#pragma unroll
      for (int mf = 0; mf < 4; mf++) {
#pragma unroll
        for (int rg = 0; rg < 4; rg++) {
          int mt = wm * 64 + mf * 16 + (lane >> 4) * 4 + rg;
          if (m0 + mt < cnt) {
            float v = acc[mf][nf][rg] + b;
            H1[(size_t)(seg + m0 + mt) * HDIM + col] = f2bf(gelu_exact(v));
          }
        }
      }
    }
  }
}

// ------------- GEMM2: out[tok] += w * (H1seg @ W2 + b2), fp32 atomics -------------
__global__ __launch_bounds__(256) void gemm2_kernel(
    const u16* __restrict__ H1, const u16* __restrict__ rw2t,
    const u16* __restrict__ sw2t, const float* __restrict__ rb2,
    const float* __restrict__ sb2, const float* __restrict__ weights,
    const int* __restrict__ counts, const int* __restrict__ segoff,
    const int* __restrict__ lists, const int* __restrict__ ytab,
    const int* __restrict__ nyt, float* __restrict__ out)
{
  __shared__ u16 Alds[128 * 64];
  __shared__ u16 Blds[128 * 64];

  int tid = threadIdx.x, wv = tid >> 6, lane = tid & 63;
  int wm = wv >> 1, wn = wv & 1;
  int col8 = (lane & 7) * 8;

  int ntile = nyt[0] * (DDIM / 128);
  for (int t = blockIdx.x; t < ntile; t += gridDim.x) {
    int yt = t >> 3, nx = t & 7;
    int em = ytab[yt];
    int e = em >> 8, m0 = (em & 255) * 128, n0 = nx * 128;
    int cnt = counts[e];
    const u16* Bt = (e < NEXP) ? (rw2t + (size_t)e * DDIM * HDIM) : sw2t;
    const float* bias = (e < NEXP) ? (rb2 + (size_t)e * DDIM) : sb2;
    const int* list = lists + e * T_TOK;
    int seg = segoff[e];

    size_t asrc[4], bsrc[4];
#pragma unroll
    for (int r = 0; r < 4; r++) {
      int srow = r * 32 + wv * 8 + (lane >> 3);
      asrc[r] = (size_t)(seg + min(m0 + srow, cnt - 1)) * HDIM + col8;
      bsrc[r] = (size_t)(n0 + srow) * HDIM + col8;
    }

    f32x4 acc[4][4];
#pragma unroll
    for (int i = 0; i < 4; i++)
#pragma unroll
      for (int j = 0; j < 4; j++) acc[i][j] = (f32x4){0.f, 0.f, 0.f, 0.f};

    for (int kk = 0; kk < HDIM; kk += 64) {
#pragma unroll
      for (int r = 0; r < 4; r++) {
        gload16(H1 + asrc[r] + kk, Alds + (size_t)(r * 256 + wv * 64 + lane) * 8);
        gload16(Bt + bsrc[r] + kk, Blds + (size_t)(r * 256 + wv * 64 + lane) * 8);
      }
      __syncthreads();
#pragma unroll
      for (int ks = 0; ks < 2; ks++) {
        int kb = ks * 32 + (lane >> 4) * 8;
        bf16x8 af[4], bfr[4];
#pragma unroll
        for (int f = 0; f < 4; f++) {
          af[f]  = *(const bf16x8*)(Alds + (wm * 64 + f * 16 + (lane & 15)) * 64 + kb);
          bfr[f] = *(const bf16x8*)(Blds + (wn * 64 + f * 16 + (lane & 15)) * 64 + kb);
        }
#pragma unroll
        for (int mf = 0; mf < 4; mf++)
#pragma unroll
          for (int nf = 0; nf < 4; nf++)
            acc[mf][nf] = __builtin_amdgcn_mfma_f32_16x16x32_bf16(af[mf], bfr[nf], acc[mf][nf], 0, 0, 0);
      }
      __syncthreads();
    }

    float biasv[4];
#pragma unroll
    for (int nf = 0; nf < 4; nf++) biasv[nf] = bias[n0 + wn * 64 + nf * 16 + (lane & 15)];

#pragma unroll
    for (int mf = 0; mf < 4; mf++) {
#pragma unroll
      for (int rg = 0; rg < 4; rg++) {
        int mt = wm * 64 + mf * 16 + (lane >> 4) * 4 + rg;
        int mrow = m0 + mt;
        if (mrow < cnt) {
          int tok = list[mrow];
          float w = (e < NEXP) ? weights[(size_t)tok * NEXP + e] : 1.0f;
          float* orow = out + (size_t)tok * DDIM + n0 + wn * 64 + (lane & 15);
#pragma unroll
          for (int nf = 0; nf < 4; nf++)
            atomicAdd(orow + nf * 16, w * (acc[mf][nf][rg] + biasv[nf]));
        }
      }
    }
  }
}

// ---------------- launcher ----------------
extern "C" void kernel_launch(void* const* d_in, const int* in_sizes, int n_in,
                              void* d_out, int out_size, void* d_ws, size_t ws_size,
                              hipStream_t stream) {
  (void)in_sizes; (void)n_in; (void)out_size; (void)ws_size;
  const float* hidden   = (const float*)d_in[0];
  const float* router_w = (const float*)d_in[1];
  const float* router_b = (const float*)d_in[2];
  const float* sw1 = (const float*)d_in[3];
  const float* sb1 = (const float*)d_in[4];
  const float* sw2 = (const float*)d_in[5];
  const float* sb2 = (const float*)d_in[6];
  const float* rw1 = (const float*)d_in[7];
  const float* rb1 = (const float*)d_in[8];
  const float* rw2 = (const float*)d_in[9];
  const float* rb2 = (const float*)d_in[10];
  float* out = (float*)d_out;

  char* ws = (char*)d_ws;
  // ws layout (bytes), all 16B aligned; total ~100.1 MB
  u16* Xb      = (u16*)(ws + 0);            //  4,194,304  [T][D] bf16
  u16* rw1t    = (u16*)(ws + 4194304);      // 33,554,432  [E][H][D] bf16 (B^T)
  u16* rw2t    = (u16*)(ws + 37748736);     // 33,554,432  [E][D][H] bf16 (B^T)
  u16* sw1t    = (u16*)(ws + 71303168);     //  4,194,304  [H][D]
  u16* sw2t    = (u16*)(ws + 75497472);     //  4,194,304  [D][H]
  u16* H1      = (u16*)(ws + 79691776);     // 25,165,824  [6144][H] bf16
  float* weights = (float*)(ws + 104857600);//     65,536  [T][E]
  int* counts  = (int*)(ws + 104923136);    //         64
  int* segoff  = (int*)(ws + 104923200);    //         64
  int* lists   = (int*)(ws + 104923264);    //     73,728  [NSEG][T]
  int* ytab    = (int*)(ws + 104996992);    //        640  [160]
  int* nyt     = (int*)(ws + 104997632);    //          4

  hipMemsetAsync(counts, 0, 64, stream);
  hipMemsetAsync(out, 0, (size_t)T_TOK * DDIM * sizeof(float), stream);

  router_kernel<<<T_TOK / 4, 256, 0, stream>>>(hidden, router_w, router_b, Xb,
                                               weights, counts, lists);
  seg_kernel<<<1, 1, 0, stream>>>(counts, segoff, ytab, nyt);

  transpose_bf16_kernel<<<dim3(HDIM / 32, DDIM / 32, NSEG), 256, 0, stream>>>(
      rw1, sw1, rw1t, sw1t, DDIM, HDIM);
  transpose_bf16_kernel<<<dim3(DDIM / 32, HDIM / 32, NSEG), 256, 0, stream>>>(
      rw2, sw2, rw2t, sw2t, HDIM, DDIM);

  gemm1_kernel<<<1024, 256, 0, stream>>>(
      Xb, rw1t, sw1t, rb1, sb1, counts, segoff, lists, ytab, nyt, H1);
  gemm2_kernel<<<1024, 256, 0, stream>>>(
      H1, rw2t, sw2t, rb2, sb2, weights, counts, segoff, lists, ytab, nyt, out);
}